// Round 2
// baseline (179.111 us; speedup 1.0000x reference)
//
#include <hip/hip_runtime.h>

#define DEVINL __device__ __forceinline__

// 3-level a-trous B3-spline UWT, fused single kernel.
// Tile: 32x64 output, staged 64x96 (halo 16 >= 14, 16B alignment).
// pack = tid&15 owns 4 consecutive cols (float4); ty = tid>>4 walks rows.
// Per level: vertical conv via 5x ds_read_b128, horizontal conv via DPP
// row_shr/row_shl (16 packs == one 16-lane DPP row, edges align with halo).
// LDS ping-pong A<->B. SW padded 64->68 floats. 2x96x68x4 = 52.2 KB -> 3 blk/CU.
//
// REGISTER PRESSURE IS THE GOVERNING CONSTRAINT: __launch_bounds__(256,3)
// caps the allocator at ~170 VGPR (512/3). Full unroll of the level loops
// keeps ~36 VGPR of load/temp state live per unrolled iter x KMAX(4..6),
// which forces scratch spills under that cap. unroll 2 keeps peak live
// state ~90 VGPR -> no spills. Do NOT raise the unroll factor without
// checking scratch in -Rpass-analysis=kernel-resource-usage.

constexpr int W_IMG = 1024;
constexpr int H_IMG = 1024;
constexpr int TX = 32;                    // output cols per tile
constexpr int TY = 64;                    // output rows per tile (GYT exact)
constexpr int HALO = 16;                  // >= 2*(1+2+4)=14
constexpr int SW = 68;                    // LDS row STRIDE in floats (64 + 4 pad)
constexpr int SH = TY + 2 * HALO;         // 96 staged rows
constexpr int GXT = W_IMG / TX;           // 32
constexpr int GYT = H_IMG / TY;           // 16 (exact)

constexpr float TP0 = 1.0f / 16.0f;
constexpr float TP1 = 1.0f / 4.0f;
constexpr float TP2 = 3.0f / 8.0f;

typedef float f32x4 __attribute__((ext_vector_type(4)));

// DPP cross-lane fetch within 16-lane rows. row_shr:n (0x110|n) = value from
// lane i-n; row_shl:n (0x100|n) = value from lane i+n. bound_ctrl=1 -> 0 at
// row edges (lands only in halo columns, never consumed by valid outputs).
template <int CTRL>
DEVINL float dppf(float x) {
    return __int_as_float(__builtin_amdgcn_update_dpp(
        0, __float_as_int(x), CTRL, 0xF, 0xF, true));
}

DEVINL int reflx(int g) {
    g = g < 0 ? -g : g;
    return g >= W_IMG ? 2 * W_IMG - 2 - g : g;
}

DEVINL void nt_store4(float* p, float a, float b, float c, float d) {
    f32x4 t;
    t.x = a; t.y = b; t.z = c; t.w = d;
    __builtin_nontemporal_store(t, (f32x4*)p);
}

// Row ranges are the EXACT dataflow need (no symmetric slack):
//   L2 (D=4) outputs rows 16..79  -> R0=16, R1=80  (4 iters, zero waste)
//   L1 (D=2) must cover 16-8..79+8 = 8..87 -> R0=8,  R1=88
//   L0 (D=1) must cover  8-4..87+4 = 4..91 -> R0=4,  R1=92
//   input staged rows 2..93 subset of 0..95.
template <int D, int R0, int R1, int LVL, bool LAST>
DEVINL void do_level(const float* src, float* dst, float* __restrict__ out,
                     int b4, int oy0, int gx0, int p, int ty) {
    const int c4 = p * 4;
    constexpr int KMAX = (R1 - R0 + 15) / 16;
#pragma unroll 2
    for (int k = 0; k < KMAX; ++k) {
        const int r = R0 + ty + 16 * k;
        if (r < R1) {  // uniform across each 16-lane DPP row (same ty)
            const float4 a0 = *(const float4*)&src[(r - 2 * D) * SW + c4];
            const float4 a1 = *(const float4*)&src[(r - D) * SW + c4];
            const float4 a2 = *(const float4*)&src[r * SW + c4];
            const float4 a3 = *(const float4*)&src[(r + D) * SW + c4];
            const float4 a4 = *(const float4*)&src[(r + 2 * D) * SW + c4];
            // vertical 5-tap
            float4 v;
            v.x = TP0 * (a0.x + a4.x) + TP1 * (a1.x + a3.x) + TP2 * a2.x;
            v.y = TP0 * (a0.y + a4.y) + TP1 * (a1.y + a3.y) + TP2 * a2.y;
            v.z = TP0 * (a0.z + a4.z) + TP1 * (a1.z + a3.z) + TP2 * a2.z;
            v.w = TP0 * (a0.w + a4.w) + TP1 * (a1.w + a3.w) + TP2 * a2.w;
            // horizontal 5-tap via DPP neighbor exchange. DPP results are
            // consumed inside one expression per component -> minimal
            // register lifetimes (spill avoidance, see header comment).
            float4 u;
            if constexpr (D == 1) {
                const float am2 = dppf<0x111>(v.z);  // col-2 for comp0
                const float am1 = dppf<0x111>(v.w);  // col-1 for comp0
                const float ap1 = dppf<0x101>(v.x);  // col+1 for comp3
                const float ap2 = dppf<0x101>(v.y);  // col+2 for comp3
                u.x = TP0 * (am2 + v.z) + TP1 * (am1 + v.y) + TP2 * v.x;
                u.y = TP0 * (am1 + v.w) + TP1 * (v.x + v.z) + TP2 * v.y;
                u.z = TP0 * (v.x + ap1) + TP1 * (v.y + v.w) + TP2 * v.z;
                u.w = TP0 * (v.y + ap2) + TP1 * (v.z + ap1) + TP2 * v.w;
            } else if constexpr (D == 2) {
                u.x = TP0 * (dppf<0x111>(v.x) + dppf<0x101>(v.x)) +
                      TP1 * (dppf<0x111>(v.z) + v.z) + TP2 * v.x;
                u.y = TP0 * (dppf<0x111>(v.y) + dppf<0x101>(v.y)) +
                      TP1 * (dppf<0x111>(v.w) + v.w) + TP2 * v.y;
                u.z = TP0 * (dppf<0x111>(v.z) + dppf<0x101>(v.z)) +
                      TP1 * (v.x + dppf<0x101>(v.x)) + TP2 * v.z;
                u.w = TP0 * (dppf<0x111>(v.w) + dppf<0x101>(v.w)) +
                      TP1 * (v.y + dppf<0x101>(v.y)) + TP2 * v.w;
            } else {  // D == 4: pure per-component, +/-1 and +/-2 lanes
                u.x = TP0 * (dppf<0x112>(v.x) + dppf<0x102>(v.x)) +
                      TP1 * (dppf<0x111>(v.x) + dppf<0x101>(v.x)) + TP2 * v.x;
                u.y = TP0 * (dppf<0x112>(v.y) + dppf<0x102>(v.y)) +
                      TP1 * (dppf<0x111>(v.y) + dppf<0x101>(v.y)) + TP2 * v.y;
                u.z = TP0 * (dppf<0x112>(v.z) + dppf<0x102>(v.z)) +
                      TP1 * (dppf<0x111>(v.z) + dppf<0x101>(v.z)) + TP2 * v.z;
                u.w = TP0 * (dppf<0x112>(v.w) + dppf<0x102>(v.w)) +
                      TP1 * (dppf<0x111>(v.w) + dppf<0x101>(v.w)) + TP2 * v.w;
            }
            // w_LVL = c_{LVL-1} - c_LVL ; a2 is the center (prev) value
            const int ly = r - HALO;
            const int oy = oy0 + ly;
            if ((unsigned)ly < (unsigned)TY && p >= 4 && p < 12) {
                const int ox = gx0 + c4 - HALO;
                const size_t base =
                    ((size_t)(b4 + LVL) * H_IMG + oy) * W_IMG + ox;
                nt_store4(&out[base], a2.x - u.x, a2.y - u.y, a2.z - u.z,
                          a2.w - u.w);
                if constexpr (LAST) {
                    const size_t base3 =
                        ((size_t)(b4 + 3) * H_IMG + oy) * W_IMG + ox;
                    nt_store4(&out[base3], u.x, u.y, u.z, u.w);  // c_3
                }
            }
            if constexpr (!LAST) *(float4*)&dst[r * SW + c4] = u;
        }
    }
}

__global__ __launch_bounds__(256, 3) void uwt3(const float* __restrict__ x,
                                               float* __restrict__ out) {
    __shared__ __align__(16) float A[SH * SW];  // 26112 B
    __shared__ __align__(16) float B[SH * SW];  // total 52224 B -> 3 blk/CU

    const int tid = threadIdx.x;
    const int p = tid & 15;
    const int ty = tid >> 4;
    int bid = blockIdx.x;
    const int bx = bid & 31;  bid >>= 5;      // GXT = 32 (pow2)
    const int by = bid & 15;                  // GYT = 16 (pow2)
    const int b = bid >> 4;
    const int oy0 = by * TY;
    const int gx0 = bx * TX;
    const float* xb = x + (size_t)b * (H_IMG * W_IMG);
    const int c4 = p * 4;
    const bool edge = (bx == 0) || (bx == GXT - 1);

    // stage 64x96 input tile with reflect halo (SH = 96 = 6*16, no remainder)
#pragma unroll 2
    for (int k = 0; k < SH / 16; ++k) {
        const int sr = ty + 16 * k;
        int gy = oy0 - HALO + sr;
        gy = gy < 0 ? -gy : gy;
        if (gy >= H_IMG) gy = 2 * H_IMG - 2 - gy;
        const float* row = xb + (size_t)gy * W_IMG;
        const int gx = gx0 - HALO + c4;
        float4 v;
        if (!edge) {
            v = *(const float4*)(row + gx);
        } else {
            v.x = row[reflx(gx)];
            v.y = row[reflx(gx + 1)];
            v.z = row[reflx(gx + 2)];
            v.w = row[reflx(gx + 3)];
        }
        *(float4*)&A[sr * SW + c4] = v;
    }
    __syncthreads();

    do_level<1, 4, 92, 0, false>(A, B, out, b * 4, oy0, gx0, p, ty);
    __syncthreads();
    do_level<2, 8, 88, 1, false>(B, A, out, b * 4, oy0, gx0, p, ty);
    __syncthreads();
    do_level<4, 16, 80, 2, true>(A, B, out, b * 4, oy0, gx0, p, ty);
}

extern "C" void kernel_launch(void* const* d_in, const int* in_sizes, int n_in,
                              void* d_out, int out_size, void* d_ws,
                              size_t ws_size, hipStream_t stream) {
    const float* x = (const float*)d_in[0];
    float* out = (float*)d_out;
    const int nb = in_sizes[0] / (H_IMG * W_IMG);  // 8
    dim3 grid(nb * GYT * GXT);                     // 8*16*32 = 4096
    uwt3<<<grid, 256, 0, stream>>>(x, out);
}